// Round 11
// baseline (27.387 us; speedup 1.0000x reference)
//
#include <hip/hip_runtime.h>
#include <hip/hip_bf16.h>

#define EPS 1e-07f

#define BLOCK 1024
#define RPB   16           // rays per block
#define NCHK  64           // K-chunks per block (tid>>4)
#define GPG   8            // groups per chunk per pass
#define CSTRIDE 196        // dwords per chunk: 8 groups*24 + 4 pad (bank skew)
#define NW    (BLOCK/64)   // 16 waves

// sqrt(0.5*log2(e)) ; log2(sqrt(2*pi))
#define SQRT_HALF_LOG2E 0.84932180028801904f
#define LOG2_SQRT_2PI   1.32574806473616588f

typedef float v4f __attribute__((ext_vector_type(4)));

// ---------------------------------------------------------------------------
// Single fused kernel, 512 blocks x 1024 threads = 2 blocks/CU, 32 waves/CU.
// Each block: 16 rays over ALL K Gaussians; K in 2 passes of 2048.
//  phase 1: block precomputes 2048 Gaussian records into LDS (cross-product
//           identity: c0 - b^2/a = (u x (p-pos))^2 / a', a' = u^T(S/detS)u).
//           Layout: 64 chunks * [8 groups * 24 + 4 pad] dwords — chunk
//           stride % 32 = 4 banks, so a wave's 4 sub-chunk b128 reads hit
//           disjoint bank quads (conflict-free).
//  phase 2: thread (ray r, chunk c) walks 8 groups, fully unrolled,
//           batched by instruction type (FMA block / rsq block / exp block),
//           4 accumulators.
//  Reduction: 2x shfl_xor + [16][16] LDS tree; plain store. No atomics.
// ---------------------------------------------------------------------------
__global__ __launch_bounds__(BLOCK, 8) void fused_splat(
        const float* __restrict__ pos_raw,
        const float* __restrict__ conc_raw,
        const float* __restrict__ scale_raw,
        const float* __restrict__ rot_raw,
        const void*  __restrict__ map_size_p,
        const float* __restrict__ p_rays,
        const float* __restrict__ u_rays,
        float* __restrict__ out,
        int K, int R)
{
    __shared__ float sG[NCHK * CSTRIDE];        // 50176 B
    __shared__ float psum[NW][RPB];

    const int tid   = threadIdx.x;
    const int lane  = tid & 63;
    const int wv    = tid >> 6;                 // 0..15
    const int rayl  = tid & (RPB - 1);          // ray within block
    const int chunk = tid >> 4;                 // 0..63

    int ray = blockIdx.x * RPB + rayl;
    if (ray >= R) ray = R - 1;

    // map_size may arrive as int32 or float32 single-element array.
    unsigned int msbits = *(const unsigned int*)map_size_p;
    float msf = __uint_as_float(msbits);
    const float ms = (msf >= 1e-3f && msf <= 1e9f) ? msf
                                                   : (float)(*(const int*)map_size_p);

    // Per-ray coefficients.
    float2 p2 = *(const float2*)(p_rays + 2*ray);
    float2 u2 = *(const float2*)(u_rays + 2*ray);
    const float p0 = p2.x, p1 = p2.y, u0 = u2.x, u1 = u2.y;
    const float qu0  = u0*u0, qu1 = 2.0f*u0*u1, qu2 = u1*u1;
    const float wt   =  SQRT_HALF_LOG2E * (u0*p1 - u1*p0);
    const float su1  =  SQRT_HALF_LOG2E * u1;
    const float nsu0 = -SQRT_HALF_LOG2E * u0;

    float acc0 = 0.0f, acc1 = 0.0f, acc2 = 0.0f, acc3 = 0.0f;

    const int KH = K >> 1;                      // 2048 per pass
    const float* cb = &sG[chunk * CSTRIDE];     // this thread's chunk base

    for (int pass = 0; pass < 2; ++pass) {
        const int kbase = pass * KH;

        __syncthreads();                        // previous pass fully consumed

        // ---- phase 1: precompute this pass's Gaussians into LDS ----
        for (int k = tid; k < KH; k += BLOCK) {
            const int kg = kbase + k;

            float pr0 = pos_raw[2*kg], pr1 = pos_raw[2*kg+1];
            float pos0 = ms / (1.0f + __expf(-pr0));
            float pos1 = ms / (1.0f + __expf(-pr1));

            float cr = conc_raw[kg];
            float conc = fmaxf(cr, 0.0f) + __logf(1.0f + __expf(-fabsf(cr)));

            float s0 = __expf(scale_raw[2*kg]);
            float s1 = __expf(scale_raw[2*kg+1]);
            float d0 = 1.0f / (s0*s0 + EPS);
            float d1 = 1.0f / (s1*s1 + EPS);

            float rot = rot_raw[kg];
            float c = __cosf(rot), s = __sinf(rot);

            float m00 = c*c*d0 + s*s*d1;
            float m01 = c*s*(d0 - d1);
            float m11 = s*s*d0 + c*c*d1;

            float det    = d0 * d1;
            float invdet = 1.0f / det;
            float cc = __log2f(conc) + LOG2_SQRT_2PI - 0.5f * __log2f(det);

            const int q = k >> 2, e = k & 3;    // group 0..511, elem 0..3
            float* rec = &sG[(q >> 3) * CSTRIDE + (q & 7) * 24];
            rec[ 0 + e] = m00 * invdet;
            rec[ 4 + e] = m01 * invdet;
            rec[ 8 + e] = m11 * invdet;
            rec[12 + e] = cc;
            rec[16 + e] = pos0;
            rec[20 + e] = pos1;
        }
        __syncthreads();

        // ---- phase 2: walk this thread's chunk (8 groups, full unroll) ----
        #pragma unroll
        for (int gq = 0; gq < GPG; ++gq) {
            const float* g = cb + gq * 24;
            v4f M00 = *(const v4f*)(g +  0);
            v4f M01 = *(const v4f*)(g +  4);
            v4f M11 = *(const v4f*)(g +  8);
            v4f CC  = *(const v4f*)(g + 12);
            v4f P0  = *(const v4f*)(g + 16);
            v4f P1  = *(const v4f*)(g + 20);

            // batched by instruction type for ILP
            v4f A, CR, RA, AR;
            #pragma unroll
            for (int e = 0; e < 4; ++e)
                A[e]  = fmaf(qu2, M11[e], fmaf(qu1, M01[e], qu0 * M00[e]));
            #pragma unroll
            for (int e = 0; e < 4; ++e)
                CR[e] = fmaf(nsu0, P1[e], fmaf(su1, P0[e], wt));
            #pragma unroll
            for (int e = 0; e < 4; ++e)
                RA[e] = __builtin_amdgcn_rsqf(A[e]);
            #pragma unroll
            for (int e = 0; e < 4; ++e) {
                float t = CR[e] * RA[e];
                AR[e] = fmaf(-t, t, CC[e]);
            }
            {
                float e0 = __builtin_amdgcn_exp2f(AR[0]);
                float e1 = __builtin_amdgcn_exp2f(AR[1]);
                float e2 = __builtin_amdgcn_exp2f(AR[2]);
                float e3 = __builtin_amdgcn_exp2f(AR[3]);
                acc0 = fmaf(RA[0], e0, acc0);
                acc1 = fmaf(RA[1], e1, acc1);
                acc2 = fmaf(RA[2], e2, acc2);
                acc3 = fmaf(RA[3], e3, acc3);
            }
        }
    }

    // ---- reduction: 64 chunk-partials per ray -> one value ----
    float a = (acc0 + acc1) + (acc2 + acc3);
    a += __shfl_xor(a, 16, 64);
    a += __shfl_xor(a, 32, 64);
    if (lane < RPB) psum[wv][lane] = a;
    __syncthreads();

    if (wv == 0 && lane < RPB) {
        float s = 0.0f;
        #pragma unroll
        for (int w = 0; w < NW; ++w) s += psum[w][lane];
        int oray = blockIdx.x * RPB + lane;
        if (oray < R) out[oray] = s;
    }
}

// ---------------------------------------------------------------------------
extern "C" void kernel_launch(void* const* d_in, const int* in_sizes, int n_in,
                              void* d_out, int out_size, void* d_ws, size_t ws_size,
                              hipStream_t stream)
{
    const float* pos_raw   = (const float*)d_in[0];
    const float* conc_raw  = (const float*)d_in[1];
    const float* scale_raw = (const float*)d_in[2];
    const float* rot_raw   = (const float*)d_in[3];
    const float* p_rays    = (const float*)d_in[4];
    const float* u_rays    = (const float*)d_in[5];
    const void*  map_size  = d_in[6];

    const int K = in_sizes[1];          // conc_raw is (K,)
    const int R = out_size;             // output is (R,)

    float* out = (float*)d_out;

    dim3 grid((R + RPB - 1) / RPB);     // 512 blocks for R=8192
    fused_splat<<<grid, BLOCK, 0, stream>>>(pos_raw, conc_raw, scale_raw,
                                            rot_raw, map_size,
                                            p_rays, u_rays, out, K, R);
}

// Round 12
// 23.919 us; speedup vs baseline: 1.1450x; 1.1450x over previous
//
#include <hip/hip_runtime.h>
#include <hip/hip_bf16.h>

#define EPS 1e-07f

#define BLOCK  256          // main kernel block (1 ray/thread)
#define NCH    64           // K-chunks (grid.y)
#define PBLOCK 64           // precompute block size

// sqrt(0.5*log2(e)) ; log2(sqrt(2*pi))
#define SQRT_HALF_LOG2E 0.84932180028801904f
#define LOG2_SQRT_2PI   1.32574806473616588f

typedef float v4f __attribute__((ext_vector_type(4)));

// ---------------------------------------------------------------------------
// Kernel 1: per-Gaussian precompute + zero d_out (identical to round 9).
// Cross-product identity: c0 - b^2/a = (u x (p-pos))^2 / a',  a' = u^T(S/detS)u
// Group-interleaved table gG[NG_PAD][24] floats (96 B per 4-Gaussian group):
//   [0..3]=m00' [4..7]=m01' [8..11]=m11' [12..15]=cc [16..19]=pos0 [20..23]=pos1
// Padded tail groups get identity records (cc=-1e38 -> exp2 -> 0 contribution).
// ---------------------------------------------------------------------------
__global__ __launch_bounds__(PBLOCK) void precompute_gauss(
                                 const float* __restrict__ pos_raw,
                                 const float* __restrict__ conc_raw,
                                 const float* __restrict__ scale_raw,
                                 const float* __restrict__ rot_raw,
                                 const void*  __restrict__ map_size_p,
                                 float* __restrict__ gG,
                                 float* __restrict__ out,
                                 int K, int KPAD, int R)
{
    int k = blockIdx.x * blockDim.x + threadIdx.x;
    int nthreads = gridDim.x * blockDim.x;

    // Zero the output (ordered before splat_main on the same stream).
    for (int i = k; i < R; i += nthreads) out[i] = 0.0f;

    if (k >= KPAD) return;

    const int q = k >> 2, e = k & 3;
    float* rec = gG + q * 24;

    if (k >= K) {               // pad: contributes exactly 0
        rec[0  + e] = 1.0f;
        rec[4  + e] = 0.0f;
        rec[8  + e] = 1.0f;
        rec[12 + e] = -1e38f;
        rec[16 + e] = 0.0f;
        rec[20 + e] = 0.0f;
        return;
    }

    // map_size may arrive as int32 or float32 single-element array.
    unsigned int msbits = *(const unsigned int*)map_size_p;
    float msf = __uint_as_float(msbits);
    const float ms = (msf >= 1e-3f && msf <= 1e9f) ? msf
                                                   : (float)(*(const int*)map_size_p);

    float pr0 = pos_raw[2*k],  pr1 = pos_raw[2*k+1];
    float pos0 = ms / (1.0f + __expf(-pr0));   // sigmoid * map_size
    float pos1 = ms / (1.0f + __expf(-pr1));

    float cr = conc_raw[k];
    float conc = fmaxf(cr, 0.0f) + __logf(1.0f + __expf(-fabsf(cr)));  // softplus

    float s0 = __expf(scale_raw[2*k]);
    float s1 = __expf(scale_raw[2*k+1]);
    float d0 = 1.0f / (s0*s0 + EPS);
    float d1 = 1.0f / (s1*s1 + EPS);

    float rot = rot_raw[k];
    float c = __cosf(rot), s = __sinf(rot);

    float m00 = c*c*d0 + s*s*d1;
    float m01 = c*s*(d0 - d1);
    float m11 = s*s*d0 + c*c*d1;

    float det    = d0 * d1;
    float invdet = 1.0f / det;
    float cc = __log2f(conc) + LOG2_SQRT_2PI - 0.5f * __log2f(det);

    rec[0  + e] = m00 * invdet;
    rec[4  + e] = m01 * invdet;
    rec[8  + e] = m11 * invdet;
    rec[12 + e] = cc;
    rec[16 + e] = pos0;
    rec[20 + e] = pos1;
}

// ---------------------------------------------------------------------------
// Kernel 2: main pairwise accumulation. Gaussian stream is wave-uniform
// (chunk = blockIdx.y), fetched through the SCALAR pipe with a software-
// pipelined double buffer in SGPRs:
//   issue B(g+1) -> compute A(g) -> wait0 -> issue A(g+2) -> compute B -> wait0
// Each lgkmcnt(0) is hidden behind ~one group of FMA work. Ordering is pinned
// by "+s" operands on the waits (WAR/RAW deps the compiler must respect).
// Zero LDS, zero vector loads in the loop.
// ---------------------------------------------------------------------------
__global__ __launch_bounds__(BLOCK, 8) void splat_main(
        const float* __restrict__ p_rays,
        const float* __restrict__ u_rays,
        const float* __restrict__ gG,
        float* __restrict__ out,
        int GPC, int R)
{
    const int ray = blockIdx.x * BLOCK + threadIdx.x;

    float2 p2 = *(const float2*)(p_rays + 2*min(ray, R-1));
    float2 u2 = *(const float2*)(u_rays + 2*min(ray, R-1));
    const float p0 = p2.x, p1 = p2.y, u0 = u2.x, u1 = u2.y;

    const float qu0  = u0*u0, qu1 = 2.0f*u0*u1, qu2 = u1*u1;
    const float wt   =  SQRT_HALF_LOG2E * (u0*p1 - u1*p0);
    const float su1  =  SQRT_HALF_LOG2E * u1;
    const float nsu0 = -SQRT_HALF_LOG2E * u0;

    float acc = 0.0f;

    const float* gp = gG + (size_t)blockIdx.y * GPC * 24;

    v4f A0, A1, A2, A3, A4, A5;
    v4f B0, B1, B2, B3, B4, B5;

#define SLOAD(b0,b1,b2,b3,b4,b5, P)                                             \
    asm volatile(                                                               \
        "s_load_dwordx4 %0, %6, 0x0\n\t"                                        \
        "s_load_dwordx4 %1, %6, 0x10\n\t"                                       \
        "s_load_dwordx4 %2, %6, 0x20\n\t"                                       \
        "s_load_dwordx4 %3, %6, 0x30\n\t"                                       \
        "s_load_dwordx4 %4, %6, 0x40\n\t"                                       \
        "s_load_dwordx4 %5, %6, 0x50"                                           \
        : "=&s"(b0), "=&s"(b1), "=&s"(b2), "=&s"(b3), "=&s"(b4), "=&s"(b5)      \
        : "s"(P))

#define SWAIT_A()                                                               \
    asm volatile("s_waitcnt lgkmcnt(0)"                                         \
        : "+s"(A0), "+s"(A1), "+s"(A2), "+s"(A3), "+s"(A4), "+s"(A5))

#define SWAIT_ALL()                                                             \
    asm volatile("s_waitcnt lgkmcnt(0)"                                         \
        : "+s"(A0), "+s"(A1), "+s"(A2), "+s"(A3), "+s"(A4), "+s"(A5),           \
          "+s"(B0), "+s"(B1), "+s"(B2), "+s"(B3), "+s"(B4), "+s"(B5))

#define COMPUTE4(M00,M01,M11,CC,P0,P1)                                          \
    {                                                                           \
        _Pragma("unroll")                                                       \
        for (int e = 0; e < 4; ++e) {                                           \
            float a_  = fmaf(qu2, (M11)[e], fmaf(qu1, (M01)[e],                 \
                                                 qu0 * (M00)[e]));              \
            float cr_ = fmaf(nsu0, (P1)[e], fmaf(su1, (P0)[e], wt));            \
            float ra_ = __builtin_amdgcn_rsqf(a_);                              \
            float t_  = cr_ * ra_;                                              \
            float ar_ = fmaf(-t_, t_, (CC)[e]);                                 \
            acc = fmaf(ra_, __builtin_amdgcn_exp2f(ar_), acc);                  \
        }                                                                       \
    }

    // Prologue: load group 0 into A and wait.
    SLOAD(A0, A1, A2, A3, A4, A5, gp);
    SWAIT_A();

    int g = 0;
    for (; g + 2 <= GPC; g += 2) {
        SLOAD(B0, B1, B2, B3, B4, B5, gp + 24);   // issue group g+1
        COMPUTE4(A0, A1, A2, A3, A4, A5);         // compute group g (hides B)
        SWAIT_ALL();                              // B valid
        SLOAD(A0, A1, A2, A3, A4, A5, gp + 48);   // issue group g+2
        COMPUTE4(B0, B1, B2, B3, B4, B5);         // compute group g+1 (hides A)
        SWAIT_ALL();                              // A valid
        gp += 48;
    }
    if (GPC & 1) {                                // odd tail: A holds group GPC-1
        COMPUTE4(A0, A1, A2, A3, A4, A5);
    }
    // Note: for even GPC the final A-load overreads 96 B past the chunk
    // (drained by the last SWAIT_ALL, values unused) — d_ws has ample slack.

#undef SLOAD
#undef SWAIT_A
#undef SWAIT_ALL
#undef COMPUTE4

    if (ray < R) atomicAdd(&out[ray], acc);
}

// ---------------------------------------------------------------------------
extern "C" void kernel_launch(void* const* d_in, const int* in_sizes, int n_in,
                              void* d_out, int out_size, void* d_ws, size_t ws_size,
                              hipStream_t stream)
{
    const float* pos_raw   = (const float*)d_in[0];
    const float* conc_raw  = (const float*)d_in[1];
    const float* scale_raw = (const float*)d_in[2];
    const float* rot_raw   = (const float*)d_in[3];
    const float* p_rays    = (const float*)d_in[4];
    const float* u_rays    = (const float*)d_in[5];
    const void*  map_size  = d_in[6];

    const int K = in_sizes[1];          // conc_raw is (K,)
    const int R = out_size;             // output is (R,)

    // Pad group count to a multiple of NCH so every chunk is uniform.
    const int ng_tot = (K + 3) / 4;
    const int GPC    = (ng_tot + NCH - 1) / NCH;   // groups per chunk
    const int ng_pad = GPC * NCH;
    const int KPAD   = ng_pad * 4;

    float* out = (float*)d_out;
    float* gG  = (float*)d_ws;          // ng_pad * 24 floats (+ overread slack)

    {
        dim3 grid((KPAD + PBLOCK - 1) / PBLOCK);
        precompute_gauss<<<grid, PBLOCK, 0, stream>>>(pos_raw, conc_raw, scale_raw,
                                                      rot_raw, map_size,
                                                      gG, out, K, KPAD, R);
    }
    {
        dim3 grid((R + BLOCK - 1) / BLOCK, NCH);
        splat_main<<<grid, BLOCK, 0, stream>>>(p_rays, u_rays, gG, out, GPC, R);
    }
}